// Round 3
// baseline (253.355 us; speedup 1.0000x reference)
//
#include <hip/hip_runtime.h>

// SparseActivation: per row of D=2048 fp32, keep top K=204 by |x|, scale by D/K.
// One WAVE per row, 32 elements/lane in registers. Exact K-th largest via
// 31-step bitwise binary search; counts accumulated per-lane in VGPRs and
// combined with a shuffle reduction (NO scalar-unit popcount chain, no LDS
// histograms, no atomics). Exact lowest-index-first tie-break (rare path).

constexpr int D_DIM = 2048;
constexpr int K_SEL = 204;     // int(2048 * 0.1)
constexpr int NT    = 256;     // 4 waves/block, one row per wave
constexpr int EPL   = 32;      // elements per lane

__device__ __forceinline__ int wave_reduce_add(int v) {
#pragma unroll
    for (int off = 32; off >= 1; off >>= 1)
        v += __shfl_xor(v, off, 64);
    return v;   // all 64 lanes hold the total
}

__global__ __launch_bounds__(NT) void sparse_topk_kernel(const float* __restrict__ x,
                                                         float* __restrict__ out) {
    const int wave = threadIdx.x >> 6;
    const int lane = threadIdx.x & 63;
    const long long row = (long long)blockIdx.x * 4 + wave;
    const float* xr = x + row * D_DIM;
    float* outr = out + row * D_DIM;

    // Element (b, lane, e): global index = 256*b + 4*lane + e, j = 4*b + e.
    float v[EPL];
    unsigned u[EPL];
    const float4* xp = reinterpret_cast<const float4*>(xr);
#pragma unroll
    for (int b = 0; b < 8; ++b) {
        const float4 f = xp[b * 64 + lane];
        v[4 * b + 0] = f.x; v[4 * b + 1] = f.y;
        v[4 * b + 2] = f.z; v[4 * b + 3] = f.w;
    }
#pragma unroll
    for (int j = 0; j < EPL; ++j) u[j] = __float_as_uint(v[j]) & 0x7fffffffu;

    // T = max value such that count(u >= T) >= K  ==  exact K-th largest abs bits.
    // T lives in a VGPR (wave-uniform by construction); no scalar round-trips.
    unsigned T = 0u;
#pragma unroll 1
    for (int bit = 30; bit >= 0; --bit) {
        const unsigned test = T | (1u << bit);
        int c0 = 0, c1 = 0, c2 = 0, c3 = 0;
#pragma unroll
        for (int j = 0; j < EPL; j += 4) {
            c0 += (u[j + 0] >= test) ? 1 : 0;
            c1 += (u[j + 1] >= test) ? 1 : 0;
            c2 += (u[j + 2] >= test) ? 1 : 0;
            c3 += (u[j + 3] >= test) ? 1 : 0;
        }
        const int cnt = wave_reduce_add((c0 + c1) + (c2 + c3));
        T = (cnt >= K_SEL) ? test : T;
    }

    // Boundary bookkeeping (packed: gt in low 16 bits, eq in high 16 bits).
    int ge_pack = 0;
#pragma unroll
    for (int j = 0; j < EPL; ++j) {
        ge_pack += (u[j] > T) ? 1 : 0;
        ge_pack += (u[j] == T) ? (1 << 16) : 0;
    }
    const int tot = wave_reduce_add(ge_pack);
    const int cnt_gt = tot & 0xFFFF;
    const int neq = tot >> 16;
    const int r = K_SEL - cnt_gt;     // equals to keep (1 <= r <= neq)

    const float scale = 2048.0f / 204.0f;

    if (neq == r) {
        // Common path: keep everything >= T.
#pragma unroll
        for (int j = 0; j < EPL; ++j) v[j] = (u[j] >= T) ? v[j] * scale : 0.0f;
    } else {
        // Rare tie path: among ==T, keep the r with lowest global index
        // (matches lax.top_k stability). Rank via equality ballots.
        const unsigned long long lt = (lane == 0) ? 0ull : (~0ull >> (64 - lane));
        int base = 0;  // equals in blocks b' < b
        for (int b = 0; b < 8; ++b) {
            unsigned long long m[4];
#pragma unroll
            for (int e = 0; e < 4; ++e) m[e] = __ballot(u[4 * b + e] == T);
            int cm = 0;  // equals in this block from lanes < lane (any e)
#pragma unroll
            for (int e = 0; e < 4; ++e) cm += __popcll(m[e] & lt);
            int partial = 0;  // equals in this block, same lane, e' < e
#pragma unroll
            for (int e = 0; e < 4; ++e) {
                const int j = 4 * b + e;
                const int rank = base + cm + partial;
                const bool eq = (u[j] == T);
                const bool sel = (u[j] > T) || (eq && rank < r);
                v[j] = sel ? v[j] * scale : 0.0f;
                partial += (int)((m[e] >> lane) & 1ull);
            }
#pragma unroll
            for (int e = 0; e < 4; ++e) base += __popcll(m[e]);
        }
    }

    float4* op = reinterpret_cast<float4*>(outr);
#pragma unroll
    for (int b = 0; b < 8; ++b)
        op[b * 64 + lane] = make_float4(v[4 * b + 0], v[4 * b + 1],
                                        v[4 * b + 2], v[4 * b + 3]);
}

extern "C" void kernel_launch(void* const* d_in, const int* in_sizes, int n_in,
                              void* d_out, int out_size, void* d_ws, size_t ws_size,
                              hipStream_t stream) {
    const float* x = (const float*)d_in[0];
    float* out = (float*)d_out;
    const int rows = in_sizes[0] / D_DIM;            // 16384
    sparse_topk_kernel<<<rows / 4, NT, 0, stream>>>(x, out);
}

// Round 4
// 240.728 us; speedup vs baseline: 1.0525x; 1.0525x over previous
//
#include <hip/hip_runtime.h>

// SparseActivation: per row of D=2048 fp32, keep top K=204 by |x|, scale by D/K.
// One WAVE per row, 32 elements/lane in registers. Exact K-th largest via
// 31-step bitwise binary search. Per-iteration wave reduction done with DPP
// row_shr/row_bcast adds (VALU, ~6 short-latency ops) instead of ds_bpermute
// shuffles (6 x ~35cyc LDS-pipe chain) -- cuts the sequential dependency that
// bounded rounds 2/3. Threshold kept scalar via readlane. Exact tie-break.

constexpr int D_DIM = 2048;
constexpr int K_SEL = 204;     // int(2048 * 0.1)
constexpr int NT    = 256;     // 4 waves/block, one row per wave
constexpr int EPL   = 32;      // elements per lane

// Full-wave64 integer sum via DPP; returns total as a wave-uniform scalar.
__device__ __forceinline__ int dpp_reduce_add(int x) {
    // row-of-16 suffix accumulation (invalid sources read 0)
    x += __builtin_amdgcn_update_dpp(0, x, 0x111, 0xF, 0xF, true);  // row_shr:1
    x += __builtin_amdgcn_update_dpp(0, x, 0x112, 0xF, 0xF, true);  // row_shr:2
    x += __builtin_amdgcn_update_dpp(0, x, 0x114, 0xF, 0xF, true);  // row_shr:4
    x += __builtin_amdgcn_update_dpp(0, x, 0x118, 0xF, 0xF, true);  // row_shr:8
    // lane15/31/47/63 now hold their row sums
    x += __builtin_amdgcn_update_dpp(0, x, 0x142, 0xA, 0xF, false); // row_bcast:15 -> rows 1,3
    x += __builtin_amdgcn_update_dpp(0, x, 0x143, 0xC, 0xF, false); // row_bcast:31 -> rows 2,3
    return __builtin_amdgcn_readlane(x, 63);                        // total
}

__global__ __launch_bounds__(NT) void sparse_topk_kernel(const float* __restrict__ x,
                                                         float* __restrict__ out) {
    const int wave = threadIdx.x >> 6;
    const int lane = threadIdx.x & 63;
    const long long row = (long long)blockIdx.x * 4 + wave;
    const float* xr = x + row * D_DIM;
    float* outr = out + row * D_DIM;

    // Element (b, lane, e): global index = 256*b + 4*lane + e, j = 4*b + e.
    float v[EPL];
    unsigned u[EPL];
    const float4* xp = reinterpret_cast<const float4*>(xr);
#pragma unroll
    for (int b = 0; b < 8; ++b) {
        const float4 f = xp[b * 64 + lane];
        v[4 * b + 0] = f.x; v[4 * b + 1] = f.y;
        v[4 * b + 2] = f.z; v[4 * b + 3] = f.w;
    }
#pragma unroll
    for (int j = 0; j < EPL; ++j) u[j] = __float_as_uint(v[j]) & 0x7fffffffu;

    // T = max value such that count(u >= T) >= K  ==  exact K-th largest abs bits.
    unsigned T = 0u;
#pragma unroll 1
    for (int bit = 30; bit >= 0; --bit) {
        const unsigned test = T | (1u << bit);
        int c = 0;
#pragma unroll
        for (int j = 0; j < EPL; ++j) c += (u[j] >= test) ? 1 : 0;
        const int cnt = dpp_reduce_add(c);
        T = (cnt >= K_SEL) ? test : T;   // uniform scalar select
    }

    // Boundary bookkeeping (packed: gt in low 16 bits, eq in high 16 bits).
    int ge_pack = 0;
#pragma unroll
    for (int j = 0; j < EPL; ++j) {
        ge_pack += (u[j] > T) ? 1 : 0;
        ge_pack += (u[j] == T) ? (1 << 16) : 0;
    }
    const int tot = dpp_reduce_add(ge_pack);
    const int cnt_gt = tot & 0xFFFF;
    const int neq = tot >> 16;
    const int r = K_SEL - cnt_gt;     // equals to keep (1 <= r <= neq)

    const float scale = 2048.0f / 204.0f;

    if (neq == r) {
        // Common path: keep everything >= T.
#pragma unroll
        for (int j = 0; j < EPL; ++j) v[j] = (u[j] >= T) ? v[j] * scale : 0.0f;
    } else {
        // Rare tie path: among ==T, keep the r with lowest global index
        // (matches lax.top_k stability). Rank via equality ballots.
        const unsigned long long lt = (lane == 0) ? 0ull : (~0ull >> (64 - lane));
        int base = 0;  // equals in blocks b' < b
        for (int b = 0; b < 8; ++b) {
            unsigned long long m[4];
#pragma unroll
            for (int e = 0; e < 4; ++e) m[e] = __ballot(u[4 * b + e] == T);
            int cm = 0;  // equals in this block from lanes < lane (any e)
#pragma unroll
            for (int e = 0; e < 4; ++e) cm += __popcll(m[e] & lt);
            int partial = 0;  // equals in this block, same lane, e' < e
#pragma unroll
            for (int e = 0; e < 4; ++e) {
                const int j = 4 * b + e;
                const int rank = base + cm + partial;
                const bool eq = (u[j] == T);
                const bool sel = (u[j] > T) || (eq && rank < r);
                v[j] = sel ? v[j] * scale : 0.0f;
                partial += (int)((m[e] >> lane) & 1ull);
            }
#pragma unroll
            for (int e = 0; e < 4; ++e) base += __popcll(m[e]);
        }
    }

    float4* op = reinterpret_cast<float4*>(outr);
#pragma unroll
    for (int b = 0; b < 8; ++b)
        op[b * 64 + lane] = make_float4(v[4 * b + 0], v[4 * b + 1],
                                        v[4 * b + 2], v[4 * b + 3]);
}

extern "C" void kernel_launch(void* const* d_in, const int* in_sizes, int n_in,
                              void* d_out, int out_size, void* d_ws, size_t ws_size,
                              hipStream_t stream) {
    const float* x = (const float*)d_in[0];
    float* out = (float*)d_out;
    const int rows = in_sizes[0] / D_DIM;            // 16384
    sparse_topk_kernel<<<rows / 4, NT, 0, stream>>>(x, out);
}

// Round 5
// 235.511 us; speedup vs baseline: 1.0758x; 1.0222x over previous
//
#include <hip/hip_runtime.h>

// SparseActivation: per row of D=2048 fp32, keep top K=204 by |x|, scale by D/K.
// One WAVE per row, 32 abs-values/lane in registers + sign bits packed into a
// single VGPR (33 live data regs -> no spills; round-4's VGPR_Count=56 vs 64
// live values forced scratch churn in the 31-iter loop). Exact K-th largest
// via bitwise binary search with DPP wave reduction, plus a wave-uniform
// EARLY EXIT when count(>=test)==K exactly (provably the exact top-K set);
// full 31-bit descent + lowest-index-first tie-break as exact fallback.

constexpr int D_DIM = 2048;
constexpr int K_SEL = 204;     // int(2048 * 0.1)
constexpr int NT    = 256;     // 4 waves/block, one row per wave
constexpr int EPL   = 32;      // elements per lane

// Full-wave64 integer sum via DPP; returns total (scalar, from lane 63).
__device__ __forceinline__ int dpp_reduce_add(int x) {
    x += __builtin_amdgcn_update_dpp(0, x, 0x111, 0xF, 0xF, true);  // row_shr:1
    x += __builtin_amdgcn_update_dpp(0, x, 0x112, 0xF, 0xF, true);  // row_shr:2
    x += __builtin_amdgcn_update_dpp(0, x, 0x114, 0xF, 0xF, true);  // row_shr:4
    x += __builtin_amdgcn_update_dpp(0, x, 0x118, 0xF, 0xF, true);  // row_shr:8
    x += __builtin_amdgcn_update_dpp(0, x, 0x142, 0xA, 0xF, false); // row_bcast:15
    x += __builtin_amdgcn_update_dpp(0, x, 0x143, 0xC, 0xF, false); // row_bcast:31
    return __builtin_amdgcn_readlane(x, 63);
}

__global__ __launch_bounds__(NT) void sparse_topk_kernel(const float* __restrict__ x,
                                                         float* __restrict__ out) {
    const int wave = threadIdx.x >> 6;
    const int lane = threadIdx.x & 63;
    const long long row = (long long)blockIdx.x * 4 + wave;
    const float* xr = x + row * D_DIM;
    float* outr = out + row * D_DIM;

    // Element (b, lane, e): global index = 256*b + 4*lane + e, j = 4*b + e.
    unsigned a[EPL];       // abs bit patterns (bit31 == 0)
    unsigned signs = 0u;   // sign bit of element j in bit j
    const float4* xp = reinterpret_cast<const float4*>(xr);
#pragma unroll
    for (int b = 0; b < 8; ++b) {
        const float4 f = xp[b * 64 + lane];
        const unsigned w0 = __float_as_uint(f.x), w1 = __float_as_uint(f.y);
        const unsigned w2 = __float_as_uint(f.z), w3 = __float_as_uint(f.w);
        a[4 * b + 0] = w0 & 0x7fffffffu; signs |= (w0 >> 31) << (4 * b + 0);
        a[4 * b + 1] = w1 & 0x7fffffffu; signs |= (w1 >> 31) << (4 * b + 1);
        a[4 * b + 2] = w2 & 0x7fffffffu; signs |= (w2 >> 31) << (4 * b + 2);
        a[4 * b + 3] = w3 & 0x7fffffffu; signs |= (w3 >> 31) << (4 * b + 3);
    }

    const float scale = 2048.0f / 204.0f;

    // Bitwise descent for the exact K-th largest abs pattern. Early exit the
    // moment count(a >= test) == K: that set IS the exact top-K (a tie
    // spanning the boundary makes count==K impossible at any test).
    unsigned T = 0u;
    unsigned thr = 0u;
    bool done = false;
#pragma unroll 1
    for (int bit = 30; bit >= 0; --bit) {
        const unsigned test = T | (1u << bit);
        int c0 = 0, c1 = 0, c2 = 0, c3 = 0;
#pragma unroll
        for (int j = 0; j < EPL; j += 4) {
            c0 += (a[j + 0] >= test) ? 1 : 0;
            c1 += (a[j + 1] >= test) ? 1 : 0;
            c2 += (a[j + 2] >= test) ? 1 : 0;
            c3 += (a[j + 3] >= test) ? 1 : 0;
        }
        const int cnt = dpp_reduce_add((c0 + c1) + (c2 + c3));
        if (cnt == K_SEL) { thr = test; done = true; break; }
        if (cnt > K_SEL) T = test;
    }

    float v[EPL];  // output values (epilogue only)

    if (done) {
        // Exact top-K set == {a >= thr}; no tie handling needed.
#pragma unroll
        for (int j = 0; j < EPL; ++j) {
            const float val =
                __uint_as_float(a[j] | (((signs >> j) & 1u) << 31)) * scale;
            v[j] = (a[j] >= thr) ? val : 0.0f;
        }
    } else {
        // T is the exact K-th largest; resolve boundary ties exactly.
        int ge_pack = 0;
#pragma unroll
        for (int j = 0; j < EPL; ++j) {
            ge_pack += (a[j] > T) ? 1 : 0;
            ge_pack += (a[j] == T) ? (1 << 16) : 0;
        }
        const int tot = dpp_reduce_add(ge_pack);
        const int cnt_gt = tot & 0xFFFF;
        const int neq = tot >> 16;
        const int r = K_SEL - cnt_gt;   // equals to keep (1 <= r <= neq)

        if (neq == r) {
#pragma unroll
            for (int j = 0; j < EPL; ++j) {
                const float val =
                    __uint_as_float(a[j] | (((signs >> j) & 1u) << 31)) * scale;
                v[j] = (a[j] >= T) ? val : 0.0f;
            }
        } else {
            // Rare: among ==T keep the r with lowest global index
            // (matches lax.top_k stability). Rank via equality ballots.
            const unsigned long long lt =
                (lane == 0) ? 0ull : (~0ull >> (64 - lane));
            int base = 0;  // equals in blocks b' < b
            for (int b = 0; b < 8; ++b) {
                unsigned long long m[4];
#pragma unroll
                for (int e = 0; e < 4; ++e) m[e] = __ballot(a[4 * b + e] == T);
                int cm = 0;  // equals in this block from lanes < lane
#pragma unroll
                for (int e = 0; e < 4; ++e) cm += __popcll(m[e] & lt);
                int partial = 0;  // equals: same lane, e' < e
#pragma unroll
                for (int e = 0; e < 4; ++e) {
                    const int j = 4 * b + e;
                    const int rank = base + cm + partial;
                    const bool eq = (a[j] == T);
                    const bool sel = (a[j] > T) || (eq && rank < r);
                    const float val =
                        __uint_as_float(a[j] | (((signs >> j) & 1u) << 31)) * scale;
                    v[j] = sel ? val : 0.0f;
                    partial += (int)((m[e] >> lane) & 1ull);
                }
#pragma unroll
                for (int e = 0; e < 4; ++e) base += __popcll(m[e]);
            }
        }
    }

    float4* op = reinterpret_cast<float4*>(outr);
#pragma unroll
    for (int b = 0; b < 8; ++b)
        op[b * 64 + lane] = make_float4(v[4 * b + 0], v[4 * b + 1],
                                        v[4 * b + 2], v[4 * b + 3]);
}

extern "C" void kernel_launch(void* const* d_in, const int* in_sizes, int n_in,
                              void* d_out, int out_size, void* d_ws, size_t ws_size,
                              hipStream_t stream) {
    const float* x = (const float*)d_in[0];
    float* out = (float*)d_out;
    const int rows = in_sizes[0] / D_DIM;            // 16384
    sparse_topk_kernel<<<rows / 4, NT, 0, stream>>>(x, out);
}